// Round 5
// baseline (293.895 us; speedup 1.0000x reference)
//
#include <hip/hip_runtime.h>
#include <hip/hip_fp16.h>
#include <cstdint>

// Problem constants (fixed by the reference)
#define BATCH  64
#define NATOMS 1024
#define DEG    5
#define FIN    256
#define OOUT   256
#define NBF    6
#define KDIM   262          // FIN + NBF
#define NKT    9            // k-tiles of 32 (K padded to 288)
#define MROWS  (BATCH * NATOMS)   // 65536
#define MT     32           // atom rows per block (legacy fused kernel)
#define AS     296          // feats row stride in shorts (592B, 16B-aligned)

#define FRAG_SHORTS (16 * NKT * 64 * 8)   // 73,728 shorts (147,456 B) per degree
#define ATH_SHORTS  ((size_t)MROWS * FIN) // fp16 atoms cache (legacy path)
#define NWBLK 216                         // 6*16*9*64 / 256 W-swizzle blocks

typedef __attribute__((ext_vector_type(8))) short bf16x8;          // MFMA A/B frag (4 VGPR)
typedef __attribute__((ext_vector_type(4))) float f32x4;           // MFMA C/D frag
typedef __attribute__((ext_vector_type(4))) unsigned short u16x4;  // bf16/fp16 quad

__device__ __forceinline__ unsigned short f2bf(float x) {
    unsigned u = __float_as_uint(x);
    u += 0x7fff + ((u >> 16) & 1);          // round-to-nearest-even
    return (unsigned short)(u >> 16);
}
__device__ __forceinline__ float bf2f(unsigned short h) {
    return __uint_as_float(((unsigned)h) << 16);
}
__device__ __forceinline__ float sigmoidf_(float x) {
    return 1.f / (1.f + __expf(-x));
}
__device__ __forceinline__ unsigned short f2h(float x) {
    return __half_as_ushort(__float2half(x));
}
__device__ __forceinline__ float h2f(unsigned short u) {
    return __half2float(__ushort_as_half(u));
}

// ---------------------------------------------------------------------------
// SPLIT PATH kernel 1: prep = W-swizzle (216 blocks) + featurize (2048 blocks).
// (unchanged from R4 — kept identical for attribution; target of next round)
// ---------------------------------------------------------------------------
__global__ __launch_bounds__(256, 8)
void prep_kernel(const float* __restrict__ degW, unsigned short* __restrict__ Wsw,
                 const float* __restrict__ atoms, const float* __restrict__ bonds,
                 const int* __restrict__ edges,
                 unsigned short* __restrict__ feats, unsigned char* __restrict__ degB)
{
    if (blockIdx.x < NWBLK) {
        const int idx = blockIdx.x * 256 + threadIdx.x;   // < 6*16*9*64 = 55296 always
        const int lane = idx & 63;
        int r = idx >> 6;
        const int t = r % NKT; r /= NKT;
        const int g = r & 15;
        const int d = r >> 4;
        const int col  = g * 16 + (lane & 15);
        const int k0   = t * 32 + (lane >> 4) * 8;
        const float* __restrict__ W = degW + (size_t)d * KDIM * OOUT;
        unsigned short* dst = Wsw + (size_t)idx * 8;
        #pragma unroll
        for (int j = 0; j < 8; ++j) {
            const int k = k0 + j;
            dst[j] = f2bf((k < KDIM) ? W[(size_t)k * OOUT + col] : 0.f);
        }
        return;
    }

    const int wid  = ((blockIdx.x - NWBLK) * 256 + (int)threadIdx.x) >> 6;  // 0..8191
    const int lane = threadIdx.x & 63;
    const int r0   = wid * 8;

    int ev[8];
    #pragma unroll
    for (int rr = 0; rr < 8; ++rr)
        ev[rr] = (lane < DEG) ? edges[(size_t)(r0 + rr) * DEG + lane] : -1;

    for (int rr = 0; rr < 8; ++rr) {
        const int row = r0 + rr;
        const float* __restrict__ abase = atoms + ((size_t)(row >> 10) << 10) * FIN;
        const int dg = (int)__popcll(__ballot(ev[rr] >= 0));

        f32x4 v = *(const f32x4*)&atoms[(size_t)row * FIN + lane * 4];
        #pragma unroll
        for (int d = 0; d < DEG; ++d) {
            const int ed = __shfl(ev[rr], d);
            const f32x4 nv = *(const f32x4*)&abase[(size_t)((ed >= 0) ? ed : 0) * FIN + lane * 4];
            const float fl = (ed >= 0) ? 1.f : 0.f;
            v.x += fl * nv.x; v.y += fl * nv.y; v.z += fl * nv.z; v.w += fl * nv.w;
        }
        u16x4 us;
        us.x = f2bf(v.x); us.y = f2bf(v.y); us.z = f2bf(v.z); us.w = f2bf(v.w);
        *(u16x4*)&feats[(size_t)row * AS + lane * 4] = us;

        float bx = (lane < DEG * NBF) ? bonds[(size_t)row * (DEG * NBF) + lane] : 0.f;
        const int kk = (lane < NBF) ? lane : 0;
        float bs = 0.f;
        #pragma unroll
        for (int p = 0; p < DEG; ++p) bs += __shfl(bx, kk + NBF * p);
        if (lane < NBF)       feats[(size_t)row * AS + FIN + lane] = f2bf(bs);
        else if (lane < 32)   feats[(size_t)row * AS + FIN + lane] = 0;   // k=262..287 must be 0
        if (lane == 0)        degB[row] = (unsigned char)dg;
    }
}

// ---------------------------------------------------------------------------
// SPLIT PATH kernel 2: ZERO-LDS, zero-barrier streaming MFMA GEMM.
// 65536x256x288, unconditional deg-5 weights; odd rows fixed by kernel 3.
// BM=32 rows/block -> 2048 blocks -> 8 waves/SIMD grid occupancy.
// Wave: 32 rows x 64 cols; A-frags read straight from global feats
// (16 rows x 64B contiguous segments per instr, L1/L2-served);
// B-frags from L2-resident swizzled Wsw.
// ---------------------------------------------------------------------------
#define BM 32
__global__ __launch_bounds__(256, 8)
void nfp_gemm_kernel(const unsigned short* __restrict__ feats,
                     const unsigned short* __restrict__ Wsw5,
                     const float* __restrict__ bias, float* __restrict__ out)
{
    const int tid  = threadIdx.x;
    const int lane = tid & 63;
    const int wave = tid >> 6;
    const int row0 = blockIdx.x * BM;
    const int fr   = lane & 15;
    const int q    = lane >> 4;
    const int wn   = wave * 64;

    float bj[4];
    #pragma unroll
    for (int j = 0; j < 4; ++j) bj[j] = bias[wn + j * 16 + fr];

    f32x4 acc[2][4];
    #pragma unroll
    for (int i = 0; i < 2; ++i)
        #pragma unroll
        for (int j = 0; j < 4; ++j)
            acc[i][j] = (f32x4){0.f, 0.f, 0.f, 0.f};

    const unsigned short* __restrict__ A0 = feats + (size_t)(row0 + fr) * AS + q * 8;
    const unsigned short* __restrict__ A1 = A0 + 16 * AS;
    const unsigned short* __restrict__ B0 = Wsw5 + ((size_t)(wave * 4) * NKT * 64 + lane) * 8;

    #pragma unroll
    for (int t = 0; t < NKT; ++t) {
        bf16x8 b[4], af[2];
        #pragma unroll
        for (int j = 0; j < 4; ++j)
            b[j] = *(const bf16x8*)&B0[(size_t)((j * NKT + t) * 64) * 8];
        af[0] = *(const bf16x8*)&A0[t * 32];
        af[1] = *(const bf16x8*)&A1[t * 32];
        #pragma unroll
        for (int i = 0; i < 2; ++i)
            #pragma unroll
            for (int j = 0; j < 4; ++j)
                acc[i][j] = __builtin_amdgcn_mfma_f32_16x16x32_bf16(af[i], b[j], acc[i][j], 0, 0, 0);
    }

    // C/D map: col=lane&15, row=(lane>>4)*4+reg
    #pragma unroll
    for (int i = 0; i < 2; ++i) {
        #pragma unroll
        for (int r = 0; r < 4; ++r) {
            const int lm = i * 16 + q * 4 + r;
            float* __restrict__ orow = out + (size_t)(row0 + lm) * OOUT + wn + fr;
            #pragma unroll
            for (int j = 0; j < 4; ++j)
                __builtin_nontemporal_store(sigmoidf_(acc[i][j][r] + bj[j]), &orow[j * 16]);
        }
    }
}

// ---------------------------------------------------------------------------
// SPLIT PATH kernel 3: odd-degree fixup. 256 blocks scan degB (256 rows each);
// for each deg!=5 row (~320 total) the whole block computes 256 cols (1/thread)
// as a 262-deep fp32 dot with L2-resident degW, overwriting the deg-5 result.
// ---------------------------------------------------------------------------
__global__ __launch_bounds__(256, 4)
void nfp_fixup_kernel(const unsigned short* __restrict__ feats,
                      const unsigned char* __restrict__ degB,
                      const float* __restrict__ degW, const float* __restrict__ bias,
                      float* __restrict__ out)
{
    __shared__ int list[256];
    __shared__ int cnt;
    const int tid = threadIdx.x;
    if (tid == 0) cnt = 0;
    __syncthreads();
    const int r = blockIdx.x * 256 + tid;
    if (degB[r] != DEG) { const int i = atomicAdd(&cnt, 1); list[i] = r; }
    __syncthreads();
    const int n = cnt;
    for (int i = 0; i < n; ++i) {
        const int row = list[i];
        const int d   = degB[row];
        const float* __restrict__ W = degW + (size_t)d * KDIM * OOUT + tid;
        const unsigned short* __restrict__ fv = feats + (size_t)row * AS;
        float s0 = 0.f, s1 = 0.f;
        #pragma unroll 4
        for (int k = 0; k < KDIM; k += 2) {                 // KDIM=262 even
            s0 += bf2f(fv[k])     * W[(size_t)k * OOUT];
            s1 += bf2f(fv[k + 1]) * W[(size_t)(k + 1) * OOUT];
        }
        out[(size_t)row * OOUT + tid] = sigmoidf_(s0 + s1 + bias[tid]);
    }
}

// ===========================================================================
// Legacy paths below (kept verified as workspace-size fallbacks)
// ===========================================================================

__global__ __launch_bounds__(256)
void convert_pre_kernel(const float* __restrict__ degW, unsigned short* __restrict__ Wsw,
                        const float* __restrict__ atoms, unsigned short* __restrict__ atomsH,
                        int nWblk)
{
    if (blockIdx.x < (unsigned)nWblk) {
        const int idx = blockIdx.x * 256 + threadIdx.x;
        if (idx >= 6 * 16 * NKT * 64) return;
        const int lane = idx & 63;
        int r = idx >> 6;
        const int t = r % NKT; r /= NKT;
        const int g = r & 15;
        const int d = r >> 4;
        const int col  = g * 16 + (lane & 15);
        const int k0   = t * 32 + (lane >> 4) * 8;
        const float* __restrict__ W = degW + (size_t)d * KDIM * OOUT;
        unsigned short* dst = Wsw + (size_t)idx * 8;
        #pragma unroll
        for (int j = 0; j < 8; ++j) {
            const int k = k0 + j;
            dst[j] = f2bf((k < KDIM) ? W[(size_t)k * OOUT + col] : 0.f);
        }
    } else {
        const int nblk = gridDim.x - nWblk;
        size_t i = (size_t)(blockIdx.x - nWblk) * 256 + threadIdx.x;
        const size_t stride = (size_t)nblk * 256;
        const size_t total = ATH_SHORTS / 4;
        const f32x4* __restrict__ src = (const f32x4*)atoms;
        u16x4* __restrict__ dst = (u16x4*)atomsH;
        for (; i < total; i += stride) {
            f32x4 v = __builtin_nontemporal_load(&src[i]);
            u16x4 h;
            h.x = f2h(v.x); h.y = f2h(v.y); h.z = f2h(v.z); h.w = f2h(v.w);
            __builtin_nontemporal_store(h, &dst[i]);
        }
    }
}

__global__ __launch_bounds__(256)
void convert_w_kernel(const float* __restrict__ degW, unsigned short* __restrict__ Wsw,
                      int all6)
{
    const int total = (all6 ? 6 : 1) * 16 * NKT * 64;
    const int idx = blockIdx.x * 256 + threadIdx.x;
    if (idx >= total) return;
    const int lane = idx & 63;
    int r = idx >> 6;
    const int t = r % NKT; r /= NKT;
    const int g = r & 15;
    const int d = r >> 4;
    const int srcd = all6 ? d : DEG;
    const int col  = g * 16 + (lane & 15);
    const int k0   = t * 32 + (lane >> 4) * 8;
    const float* __restrict__ W = degW + (size_t)srcd * KDIM * OOUT;
    unsigned short* dst = Wsw + (size_t)idx * 8;
    #pragma unroll
    for (int j = 0; j < 8; ++j) {
        const int k = k0 + j;
        dst[j] = f2bf((k < KDIM) ? W[(size_t)k * OOUT + col] : 0.f);
    }
}

template <int MODE>
__global__ __launch_bounds__(256, 4)
void nfp_fused_kernel(const float* __restrict__ atoms, const unsigned short* __restrict__ atomsH,
                      const float* __restrict__ bonds, const int* __restrict__ edges,
                      const unsigned short* __restrict__ Wsw, const float* __restrict__ degW,
                      const float* __restrict__ bias, float* __restrict__ out)
{
    constexpr bool FP16N = (MODE == 2);
    constexpr bool ALL6  = (MODE >= 1);

    __shared__ short Afeat[MT * AS];
    __shared__ int   edg[MT * DEG];
    __shared__ int   deg_lds[MT];
    __shared__ int   degmask;

    const int tid  = threadIdx.x;
    const int lane = tid & 63;
    const int wave = tid >> 6;

    const int bid   = blockIdx.x;
    const int xcd   = bid & 7;
    const int per   = bid >> 3;
    const int batch = (per >> 5) * 8 + xcd;
    const int blk   = per & 31;
    const int row0  = batch * NATOMS + blk * MT;

    if (tid == 0) degmask = 0;
    if (tid < MT * DEG) edg[tid] = edges[row0 * DEG + tid];
    __syncthreads();
    if (tid < MT) {
        int dc = 0;
        #pragma unroll
        for (int d = 0; d < DEG; ++d) dc += (edg[tid * DEG + d] != -1) ? 1 : 0;
        deg_lds[tid] = dc;
        atomicOr(&degmask, 1 << dc);
    }

    const float* __restrict__ abase = atoms + ((size_t)batch << 10) * FIN;
    const unsigned short* __restrict__ hbase =
        FP16N ? atomsH + ((size_t)batch << 10) * FIN : atomsH;
    const int selfrow = blk * MT;
    const int mw = wave * 8;

#define GATHER_CHUNK(MB, NR)                                                          \
    {                                                                                 \
        f32x4 self[NR]; int msk[NR];                                                  \
        u16x4 nh[NR][DEG]; f32x4 nv[NR][DEG];                                         \
        _Pragma("unroll")                                                             \
        for (int r = 0; r < NR; ++r) {                                                \
            const int m = (MB) + r;                                                   \
            msk[r] = 0;                                                               \
            self[r] = __builtin_nontemporal_load(                                     \
                (const f32x4*)&abase[(size_t)(selfrow + m) * FIN + lane * 4]);        \
            _Pragma("unroll")                                                         \
            for (int d = 0; d < DEG; ++d) {                                           \
                const int e = edg[m * DEG + d];                                       \
                msk[r] |= (e >= 0) ? (1 << d) : 0;                                    \
                const int ei = (e >= 0) ? e : 0;                                      \
                if constexpr (FP16N)                                                  \
                    nh[r][d] = *(const u16x4*)&hbase[(size_t)ei * FIN + lane * 4];    \
                else                                                                  \
                    nv[r][d] = *(const f32x4*)&abase[(size_t)ei * FIN + lane * 4];    \
            }                                                                         \
        }                                                                             \
        _Pragma("unroll")                                                             \
        for (int r = 0; r < NR; ++r) {                                                \
            const int m = (MB) + r;                                                   \
            f32x4 v = self[r];                                                        \
            _Pragma("unroll")                                                         \
            for (int d = 0; d < DEG; ++d) {                                           \
                const float fl = ((msk[r] >> d) & 1) ? 1.f : 0.f;                     \
                if constexpr (FP16N) {                                                \
                    v.x += fl * h2f(nh[r][d].x); v.y += fl * h2f(nh[r][d].y);         \
                    v.z += fl * h2f(nh[r][d].z); v.w += fl * h2f(nh[r][d].w);         \
                } else {                                                              \
                    v.x += fl * nv[r][d].x; v.y += fl * nv[r][d].y;                   \
                    v.z += fl * nv[r][d].z; v.w += fl * nv[r][d].w;                   \
                }                                                                     \
            }                                                                         \
            u16x4 us;                                                                 \
            us.x = f2bf(v.x); us.y = f2bf(v.y); us.z = f2bf(v.z); us.w = f2bf(v.w);   \
            *(u16x4*)&Afeat[m * AS + lane * 4] = us;                                  \
        }                                                                             \
    }

    GATHER_CHUNK(mw + 0, 3)
    GATHER_CHUNK(mw + 3, 3)
    GATHER_CHUNK(mw + 6, 2)
#undef GATHER_CHUNK

    {
        const int mz = mw + (lane >> 3), pz = lane & 7;
        u16x4 zz = {0, 0, 0, 0};
        *(u16x4*)&Afeat[mz * AS + FIN + pz * 4] = zz;
        if (lane < 48) {
            const int r  = lane / 6;
            const int kk = lane - r * 6;
            const int m  = mw + r;
            const float* __restrict__ bb = bonds + ((size_t)(row0 + m)) * (DEG * NBF) + kk;
            const float bv = bb[0] + bb[NBF] + bb[2 * NBF] + bb[3 * NBF] + bb[4 * NBF];
            Afeat[m * AS + FIN + kk] = f2bf(bv);
        }
    }

    const unsigned short* __restrict__ Wb5 =
        Wsw + (ALL6 ? (size_t)DEG * FRAG_SHORTS : (size_t)0);
    const int fr = lane & 15;
    const int q  = lane >> 4;
    const int wn = wave * 64;

    bf16x8 b0[4];
    #pragma unroll
    for (int j = 0; j < 4; ++j)
        b0[j] = *(const bf16x8*)&Wb5[((size_t)((wave * 4 + j) * NKT) * 64 + lane) * 8];

    __syncthreads();

    auto gemm_pass = [&](const unsigned short* __restrict__ Wb, bf16x8 (&bini)[4],
                         f32x4 (&a)[2][4]) {
        bf16x8 bcur[4], bnxt[4], acur[2], anxt[2];
        #pragma unroll
        for (int j = 0; j < 4; ++j) bcur[j] = bini[j];
        #pragma unroll
        for (int i = 0; i < 2; ++i)
            acur[i] = *(const bf16x8*)&Afeat[(i * 16 + fr) * AS + q * 8];
        #pragma unroll
        for (int t = 0; t < NKT; ++t) {
            if (t + 1 < NKT) {
                #pragma unroll
                for (int j = 0; j < 4; ++j)
                    bnxt[j] = *(const bf16x8*)&Wb[((size_t)((wave * 4 + j) * NKT + t + 1) * 64 + lane) * 8];
                #pragma unroll
                for (int i = 0; i < 2; ++i)
                    anxt[i] = *(const bf16x8*)&Afeat[(i * 16 + fr) * AS + (t + 1) * 32 + q * 8];
            }
            #pragma unroll
            for (int i = 0; i < 2; ++i)
                #pragma unroll
                for (int j = 0; j < 4; ++j)
                    a[i][j] = __builtin_amdgcn_mfma_f32_16x16x32_bf16(acur[i], bcur[j], a[i][j], 0, 0, 0);
            if (t + 1 < NKT) {
                #pragma unroll
                for (int j = 0; j < 4; ++j) bcur[j] = bnxt[j];
                #pragma unroll
                for (int i = 0; i < 2; ++i) acur[i] = anxt[i];
            }
        }
    };

    auto epilogue = [&](f32x4 (&a)[2][4], int want) {
        #pragma unroll
        for (int j = 0; j < 4; ++j) {
            const int gn = wn + j * 16 + fr;
            const float bjv = bias[gn];
            #pragma unroll
            for (int i = 0; i < 2; ++i) {
                #pragma unroll
                for (int r = 0; r < 4; ++r) {
                    const int lm = i * 16 + q * 4 + r;
                    if (deg_lds[lm] == want)
                        __builtin_nontemporal_store(sigmoidf_(a[i][j][r] + bjv),
                                                    &out[((size_t)row0 + lm) * OOUT + gn]);
                }
            }
        }
    };

    f32x4 acc[2][4];
    #pragma unroll
    for (int i = 0; i < 2; ++i)
        #pragma unroll
        for (int j = 0; j < 4; ++j)
            acc[i][j] = (f32x4){0.f, 0.f, 0.f, 0.f};

    gemm_pass(Wb5, b0, acc);
    epilogue(acc, DEG);

    int dmask = degmask & 0x1F;
    if (dmask == 0) return;

    if constexpr (ALL6) {
        while (dmask) {
            const int d = __ffs(dmask) - 1;
            dmask &= dmask - 1;
            const unsigned short* __restrict__ Wd = Wsw + (size_t)d * FRAG_SHORTS;
            bf16x8 bd[4];
            #pragma unroll
            for (int j = 0; j < 4; ++j)
                bd[j] = *(const bf16x8*)&Wd[((size_t)((wave * 4 + j) * NKT) * 64 + lane) * 8];
            f32x4 a2[2][4];
            #pragma unroll
            for (int i = 0; i < 2; ++i)
                #pragma unroll
                for (int j = 0; j < 4; ++j)
                    a2[i][j] = (f32x4){0.f, 0.f, 0.f, 0.f};
            gemm_pass(Wd, bd, a2);
            epilogue(a2, d);
        }
    } else {
        for (int m = 0; m < MT; ++m) {
            const int dg = deg_lds[m];
            if (dg == DEG) continue;
            const float* __restrict__ W = degW + (size_t)dg * KDIM * OOUT;
            float s0 = 0.f, s1 = 0.f, s2 = 0.f, s3 = 0.f;
            #pragma unroll 2
            for (int k = 0; k < 260; k += 4) {
                const float w0 = W[(size_t)(k + 0) * OOUT + tid];
                const float w1 = W[(size_t)(k + 1) * OOUT + tid];
                const float w2 = W[(size_t)(k + 2) * OOUT + tid];
                const float w3 = W[(size_t)(k + 3) * OOUT + tid];
                s0 += bf2f(Afeat[m * AS + k + 0]) * w0;
                s1 += bf2f(Afeat[m * AS + k + 1]) * w1;
                s2 += bf2f(Afeat[m * AS + k + 2]) * w2;
                s3 += bf2f(Afeat[m * AS + k + 3]) * w3;
            }
            s0 += bf2f(Afeat[m * AS + 260]) * W[(size_t)260 * OOUT + tid];
            s1 += bf2f(Afeat[m * AS + 261]) * W[(size_t)261 * OOUT + tid];
            const float x = ((s0 + s1) + (s2 + s3)) + bias[tid];
            out[((size_t)row0 + m) * OOUT + tid] = sigmoidf_(x);
        }
    }
}

#define FMT  32
#define FKT  32
#define FKPAD 288
__global__ __launch_bounds__(256, 2)
void nfp_conv_fallback(const float* __restrict__ atoms, const float* __restrict__ bonds,
                       const int* __restrict__ edges, const float* __restrict__ degW,
                       const float* __restrict__ bias, float* __restrict__ out)
{
    __shared__ float feats[FMT * FKPAD];
    __shared__ float wtile[FKT * OOUT];
    __shared__ int   edg[FMT * DEG];
    __shared__ int   deg_lds[FMT];
    __shared__ int   odd_list[FMT];
    __shared__ int   odd_cnt;
    __shared__ float b_lds[OOUT];

    const int tid = threadIdx.x, bid = blockIdx.x;
    const int batch = bid >> 5, a0 = (bid & 31) * FMT;
    const size_t atom_base = (size_t)batch * NATOMS;

    b_lds[tid] = bias[tid];
    if (tid == 0) odd_cnt = 0;
    if (tid < FMT * DEG) {
        const int m = tid / DEG, d = tid % DEG;
        edg[tid] = edges[(atom_base + a0 + m) * DEG + d];
    }
    __syncthreads();
    if (tid < FMT) {
        int dc = 0;
        #pragma unroll
        for (int d = 0; d < DEG; ++d) dc += (edg[tid * DEG + d] != -1) ? 1 : 0;
        deg_lds[tid] = dc;
        if (dc != DEG) { const int idx = atomicAdd(&odd_cnt, 1); odd_list[idx] = tid; }
    }
    __syncthreads();
    {
        const int f = tid;
        for (int m = 0; m < FMT; ++m) {
            float v = atoms[(atom_base + a0 + m) * FIN + f];
            #pragma unroll
            for (int d = 0; d < DEG; ++d) {
                const int e = edg[m * DEG + d];
                if (e >= 0) v += atoms[(atom_base + e) * FIN + f];
            }
            feats[m * FKPAD + f] = v;
        }
        #pragma unroll
        for (int t = 0; t < 4; ++t) {
            const int idx = t * 256 + tid;
            const int m = idx >> 5, kk = idx & 31;
            float v = 0.f;
            if (kk < NBF) {
                const size_t bb = (atom_base + a0 + m) * (size_t)(DEG * NBF);
                #pragma unroll
                for (int d = 0; d < DEG; ++d) v += bonds[bb + d * NBF + kk];
            }
            feats[m * FKPAD + FIN + kk] = v;
        }
    }
    const float* __restrict__ W5 = degW + (size_t)DEG * KDIM * OOUT;
    float acc[4][8];
    #pragma unroll
    for (int i = 0; i < 4; ++i)
        #pragma unroll
        for (int j = 0; j < 8; ++j) acc[i][j] = 0.f;
    const int tx = tid & 31, ty = tid >> 5;
    for (int kt = 0; kt < FKPAD; kt += FKT) {
        __syncthreads();
        #pragma unroll
        for (int t = 0; t < FKT; ++t) {
            const int k = kt + t;
            wtile[t * OOUT + tid] = (k < KDIM) ? W5[(size_t)k * OOUT + tid] : 0.f;
        }
        __syncthreads();
        #pragma unroll 4
        for (int r = 0; r < FKT; ++r) {
            float a_frag[4];
            #pragma unroll
            for (int i = 0; i < 4; ++i) a_frag[i] = feats[(ty * 4 + i) * FKPAD + kt + r];
            float w_frag[8];
            #pragma unroll
            for (int j = 0; j < 8; ++j) w_frag[j] = wtile[r * OOUT + tx + j * 32];
            #pragma unroll
            for (int i = 0; i < 4; ++i)
                #pragma unroll
                for (int j = 0; j < 8; ++j) acc[i][j] += a_frag[i] * w_frag[j];
        }
    }
    #pragma unroll
    for (int i = 0; i < 4; ++i) {
        const int m = ty * 4 + i;
        if (deg_lds[m] == DEG) {
            const size_t row = (atom_base + a0 + m) * (size_t)OOUT;
            #pragma unroll
            for (int j = 0; j < 8; ++j) {
                const int o = tx + j * 32;
                out[row + o] = sigmoidf_(acc[i][j] + b_lds[o]);
            }
        }
    }
    const int ocnt = odd_cnt;
    for (int i = 0; i < ocnt; ++i) {
        const int m = odd_list[i], d = deg_lds[m];
        const float* __restrict__ W = degW + (size_t)d * KDIM * OOUT;
        float a2 = 0.f;
        for (int k = 0; k < KDIM; ++k) a2 += feats[m * FKPAD + k] * W[(size_t)k * OOUT + tid];
        const size_t row = (atom_base + a0 + m) * (size_t)OOUT;
        out[row + tid] = sigmoidf_(a2 + b_lds[tid]);
    }
}

// ---------------------------------------------------------------------------
extern "C" void kernel_launch(void* const* d_in, const int* in_sizes, int n_in,
                              void* d_out, int out_size, void* d_ws, size_t ws_size,
                              hipStream_t stream) {
    const float* atoms = (const float*)d_in[0];
    const float* bonds = (const float*)d_in[1];
    const int*   edges = (const int*)d_in[2];
    const float* degW  = (const float*)d_in[3];
    const float* bias  = (const float*)d_in[4];
    float* out = (float*)d_out;

    const size_t WSW_ONE = (size_t)FRAG_SHORTS * 2;      // 147,456 B
    const size_t WSW_ALL = (size_t)6 * FRAG_SHORTS * 2;  // 884,736 B
    const size_t ATH_B   = ATH_SHORTS * 2;               // 33,554,432 B
    const size_t FEATS_B = (size_t)MROWS * AS * 2;       // 38,797,312 B
    const size_t NEED_SPLIT = WSW_ALL + FEATS_B + (size_t)MROWS;  // 39,747,584 B

    if (ws_size >= NEED_SPLIT) {
        // Split path: featurize -> zero-LDS streaming GEMM -> odd-row fixup.
        unsigned short* Wsw   = (unsigned short*)d_ws;
        unsigned short* feats = (unsigned short*)((char*)d_ws + WSW_ALL);
        unsigned char*  degB  = (unsigned char*)((char*)d_ws + WSW_ALL + FEATS_B);
        prep_kernel<<<NWBLK + MROWS / (4 * 8), 256, 0, stream>>>(   // 216 + 2048
            degW, Wsw, atoms, bonds, edges, feats, degB);
        nfp_gemm_kernel<<<MROWS / BM, 256, 0, stream>>>(            // 2048 blocks
            feats, Wsw + (size_t)DEG * FRAG_SHORTS, bias, out);
        nfp_fixup_kernel<<<MROWS / 256, 256, 0, stream>>>(          // 256 blocks
            feats, degB, degW, bias, out);
    } else if (ws_size >= WSW_ALL + ATH_B) {
        unsigned short* Wsw    = (unsigned short*)d_ws;
        unsigned short* atomsH = (unsigned short*)((char*)d_ws + WSW_ALL);
        const int nWblk = (6 * 16 * NKT * 64 + 255) / 256;
        convert_pre_kernel<<<nWblk + 2048, 256, 0, stream>>>(degW, Wsw, atoms, atomsH, nWblk);
        nfp_fused_kernel<2><<<MROWS / MT, 256, 0, stream>>>(
            atoms, atomsH, bonds, edges, Wsw, degW, bias, out);
    } else if (ws_size >= WSW_ALL) {
        unsigned short* Wsw = (unsigned short*)d_ws;
        convert_w_kernel<<<(6 * 16 * NKT * 64 + 255) / 256, 256, 0, stream>>>(degW, Wsw, 1);
        nfp_fused_kernel<1><<<MROWS / MT, 256, 0, stream>>>(
            atoms, nullptr, bonds, edges, Wsw, degW, bias, out);
    } else if (ws_size >= WSW_ONE) {
        unsigned short* Wsw = (unsigned short*)d_ws;
        convert_w_kernel<<<(16 * NKT * 64 + 255) / 256, 256, 0, stream>>>(degW, Wsw, 0);
        nfp_fused_kernel<0><<<MROWS / MT, 256, 0, stream>>>(
            atoms, nullptr, bonds, edges, Wsw, degW, bias, out);
    } else {
        nfp_conv_fallback<<<BATCH * (NATOMS / FMT), 256, 0, stream>>>(
            atoms, bonds, edges, degW, bias, out);
    }
}

// Round 6
// 242.260 us; speedup vs baseline: 1.2131x; 1.2131x over previous
//
#include <hip/hip_runtime.h>
#include <hip/hip_fp16.h>
#include <cstdint>

// Problem constants (fixed by the reference)
#define BATCH  64
#define NATOMS 1024
#define DEG    5
#define FIN    256
#define OOUT   256
#define NBF    6
#define KDIM   262          // FIN + NBF
#define NKT    9            // k-tiles of 32 (K padded to 288)
#define MROWS  (BATCH * NATOMS)   // 65536
#define MT     32           // atom rows per block (legacy fused kernel)
#define AS     296          // feats row stride in shorts (592B, 16B-aligned)

#define FRAG_SHORTS (16 * NKT * 64 * 8)   // 73,728 shorts (147,456 B) per degree
#define ATH_SHORTS  ((size_t)MROWS * FIN) // fp16 atoms cache (legacy path)
#define NWBLK 216                         // 6*16*9*64 / 256 W-swizzle blocks

typedef __attribute__((ext_vector_type(8))) short bf16x8;          // MFMA A/B frag (4 VGPR)
typedef __attribute__((ext_vector_type(4))) float f32x4;           // MFMA C/D frag
typedef __attribute__((ext_vector_type(4))) unsigned short u16x4;  // bf16/fp16 quad

__device__ __forceinline__ unsigned short f2bf(float x) {
    unsigned u = __float_as_uint(x);
    u += 0x7fff + ((u >> 16) & 1);          // round-to-nearest-even
    return (unsigned short)(u >> 16);
}
__device__ __forceinline__ float bf2f(unsigned short h) {
    return __uint_as_float(((unsigned)h) << 16);
}
__device__ __forceinline__ float sigmoidf_(float x) {
    return 1.f / (1.f + __expf(-x));
}
__device__ __forceinline__ unsigned short f2h(float x) {
    return __half_as_ushort(__float2half(x));
}
__device__ __forceinline__ float h2f(unsigned short u) {
    return __half2float(__ushort_as_half(u));
}

// ---------------------------------------------------------------------------
// SPLIT PATH kernel 1: prep = W-swizzle (216 blocks) + featurize (2048 blocks).
// (unchanged from R4/R5 — frozen for attribution; next optimization target)
// ---------------------------------------------------------------------------
__global__ __launch_bounds__(256, 8)
void prep_kernel(const float* __restrict__ degW, unsigned short* __restrict__ Wsw,
                 const float* __restrict__ atoms, const float* __restrict__ bonds,
                 const int* __restrict__ edges,
                 unsigned short* __restrict__ feats, unsigned char* __restrict__ degB)
{
    if (blockIdx.x < NWBLK) {
        const int idx = blockIdx.x * 256 + threadIdx.x;   // < 6*16*9*64 = 55296 always
        const int lane = idx & 63;
        int r = idx >> 6;
        const int t = r % NKT; r /= NKT;
        const int g = r & 15;
        const int d = r >> 4;
        const int col  = g * 16 + (lane & 15);
        const int k0   = t * 32 + (lane >> 4) * 8;
        const float* __restrict__ W = degW + (size_t)d * KDIM * OOUT;
        unsigned short* dst = Wsw + (size_t)idx * 8;
        #pragma unroll
        for (int j = 0; j < 8; ++j) {
            const int k = k0 + j;
            dst[j] = f2bf((k < KDIM) ? W[(size_t)k * OOUT + col] : 0.f);
        }
        return;
    }

    const int wid  = ((blockIdx.x - NWBLK) * 256 + (int)threadIdx.x) >> 6;  // 0..8191
    const int lane = threadIdx.x & 63;
    const int r0   = wid * 8;

    int ev[8];
    #pragma unroll
    for (int rr = 0; rr < 8; ++rr)
        ev[rr] = (lane < DEG) ? edges[(size_t)(r0 + rr) * DEG + lane] : -1;

    for (int rr = 0; rr < 8; ++rr) {
        const int row = r0 + rr;
        const float* __restrict__ abase = atoms + ((size_t)(row >> 10) << 10) * FIN;
        const int dg = (int)__popcll(__ballot(ev[rr] >= 0));

        f32x4 v = *(const f32x4*)&atoms[(size_t)row * FIN + lane * 4];
        #pragma unroll
        for (int d = 0; d < DEG; ++d) {
            const int ed = __shfl(ev[rr], d);
            const f32x4 nv = *(const f32x4*)&abase[(size_t)((ed >= 0) ? ed : 0) * FIN + lane * 4];
            const float fl = (ed >= 0) ? 1.f : 0.f;
            v.x += fl * nv.x; v.y += fl * nv.y; v.z += fl * nv.z; v.w += fl * nv.w;
        }
        u16x4 us;
        us.x = f2bf(v.x); us.y = f2bf(v.y); us.z = f2bf(v.z); us.w = f2bf(v.w);
        *(u16x4*)&feats[(size_t)row * AS + lane * 4] = us;

        float bx = (lane < DEG * NBF) ? bonds[(size_t)row * (DEG * NBF) + lane] : 0.f;
        const int kk = (lane < NBF) ? lane : 0;
        float bs = 0.f;
        #pragma unroll
        for (int p = 0; p < DEG; ++p) bs += __shfl(bx, kk + NBF * p);
        if (lane < NBF)       feats[(size_t)row * AS + FIN + lane] = f2bf(bs);
        else if (lane < 32)   feats[(size_t)row * AS + FIN + lane] = 0;   // k=262..287 must be 0
        if (lane == 0)        degB[row] = (unsigned char)dg;
    }
}

// ---------------------------------------------------------------------------
// SPLIT PATH kernel 2 (R6): streaming MFMA GEMM, register-pipelined.
//  - __launch_bounds__(256,4): 128-VGPR budget -> explicit A/B double-buffer
//    keeps ~6 loads in flight per wave (R5's 64-reg cap serialized everything)
//  - epilogue: XOR-swizzled LDS transpose of the finished 32x256 f32 tile,
//    then fully-coalesced 1024B-per-wave nt stores (R5 nt-scatter cost 2.5x
//    write amplification: 170 MB vs 67 MB ideal)
// ---------------------------------------------------------------------------
#define BM 32
__global__ __launch_bounds__(256, 4)
void nfp_gemm_kernel(const unsigned short* __restrict__ feats,
                     const unsigned short* __restrict__ Wsw5,
                     const float* __restrict__ bias, float* __restrict__ out)
{
    __shared__ float Ct[BM * OOUT];   // 32,768 B

    const int tid  = threadIdx.x;
    const int lane = tid & 63;
    const int wave = tid >> 6;
    const int row0 = blockIdx.x * BM;
    const int fr   = lane & 15;
    const int q    = lane >> 4;
    const int wn   = wave * 64;

    f32x4 acc[2][4];
    #pragma unroll
    for (int i = 0; i < 2; ++i)
        #pragma unroll
        for (int j = 0; j < 4; ++j)
            acc[i][j] = (f32x4){0.f, 0.f, 0.f, 0.f};

    const unsigned short* __restrict__ A0 = feats + (size_t)(row0 + fr) * AS + q * 8;
    const unsigned short* __restrict__ A1 = A0 + 16 * AS;
    const unsigned short* __restrict__ B0 = Wsw5 + ((size_t)(wave * 4) * NKT * 64 + lane) * 8;

    auto ldb = [&](int j, int t) {
        return *(const bf16x8*)&B0[(size_t)((j * NKT + t) * 64) * 8];
    };

    bf16x8 bc[4], bn[4], ac[2], an[2];
    #pragma unroll
    for (int j = 0; j < 4; ++j) bc[j] = ldb(j, 0);
    ac[0] = *(const bf16x8*)&A0[0];
    ac[1] = *(const bf16x8*)&A1[0];

    #pragma unroll
    for (int t = 0; t < NKT; ++t) {
        if (t + 1 < NKT) {                         // prefetch next k-tile
            #pragma unroll
            for (int j = 0; j < 4; ++j) bn[j] = ldb(j, t + 1);
            an[0] = *(const bf16x8*)&A0[(t + 1) * 32];
            an[1] = *(const bf16x8*)&A1[(t + 1) * 32];
        }
        #pragma unroll
        for (int i = 0; i < 2; ++i)
            #pragma unroll
            for (int j = 0; j < 4; ++j)
                acc[i][j] = __builtin_amdgcn_mfma_f32_16x16x32_bf16(ac[i], bc[j], acc[i][j], 0, 0, 0);
        if (t + 1 < NKT) {
            #pragma unroll
            for (int j = 0; j < 4; ++j) bc[j] = bn[j];
            ac[0] = an[0]; ac[1] = an[1];
        }
    }

    // ---- epilogue 1: bias+sigmoid -> swizzled LDS ----
    // C/D map: col=lane&15 (+j*16+wn), row lm=i*16+q*4+r. Bank-swizzle:
    // col ^= ((lm>>2)&3)<<4 so the 4 q-groups of one store hit distinct
    // 16-bank sets (2-way residue only, which is free).
    float bj[4];
    #pragma unroll
    for (int j = 0; j < 4; ++j) bj[j] = bias[wn + j * 16 + fr];

    #pragma unroll
    for (int i = 0; i < 2; ++i) {
        #pragma unroll
        for (int r = 0; r < 4; ++r) {
            const int lm = i * 16 + q * 4 + r;
            const int sw = ((lm >> 2) & 3) << 4;
            #pragma unroll
            for (int j = 0; j < 4; ++j)
                Ct[lm * OOUT + ((wn + j * 16 + fr) ^ sw)] = sigmoidf_(acc[i][j][r] + bj[j]);
        }
    }
    __syncthreads();

    // ---- epilogue 2: coalesced full-line streaming stores ----
    // 8192 floats = 2048 f32x4; thread c*256+tid -> row=v>>6, unswizzle c4.
    const f32x4* __restrict__ src = (const f32x4*)Ct;
    f32x4* __restrict__ dst = (f32x4*)(out + (size_t)row0 * OOUT);
    #pragma unroll
    for (int c = 0; c < 8; ++c) {
        const int v   = c * 256 + tid;
        const int row = v >> 6;
        const int c4  = v & 63;
        const int c4s = c4 ^ (((row >> 2) & 3) << 2);
        __builtin_nontemporal_store(src[row * 64 + c4s], &dst[v]);
    }
}

// ---------------------------------------------------------------------------
// SPLIT PATH kernel 3: odd-degree fixup (unchanged from R5).
// ---------------------------------------------------------------------------
__global__ __launch_bounds__(256, 4)
void nfp_fixup_kernel(const unsigned short* __restrict__ feats,
                      const unsigned char* __restrict__ degB,
                      const float* __restrict__ degW, const float* __restrict__ bias,
                      float* __restrict__ out)
{
    __shared__ int list[256];
    __shared__ int cnt;
    const int tid = threadIdx.x;
    if (tid == 0) cnt = 0;
    __syncthreads();
    const int r = blockIdx.x * 256 + tid;
    if (degB[r] != DEG) { const int i = atomicAdd(&cnt, 1); list[i] = r; }
    __syncthreads();
    const int n = cnt;
    for (int i = 0; i < n; ++i) {
        const int row = list[i];
        const int d   = degB[row];
        const float* __restrict__ W = degW + (size_t)d * KDIM * OOUT + tid;
        const unsigned short* __restrict__ fv = feats + (size_t)row * AS;
        float s0 = 0.f, s1 = 0.f;
        #pragma unroll 4
        for (int k = 0; k < KDIM; k += 2) {                 // KDIM=262 even
            s0 += bf2f(fv[k])     * W[(size_t)k * OOUT];
            s1 += bf2f(fv[k + 1]) * W[(size_t)(k + 1) * OOUT];
        }
        out[(size_t)row * OOUT + tid] = sigmoidf_(s0 + s1 + bias[tid]);
    }
}

// ===========================================================================
// Legacy paths below (kept verified as workspace-size fallbacks)
// ===========================================================================

__global__ __launch_bounds__(256)
void convert_pre_kernel(const float* __restrict__ degW, unsigned short* __restrict__ Wsw,
                        const float* __restrict__ atoms, unsigned short* __restrict__ atomsH,
                        int nWblk)
{
    if (blockIdx.x < (unsigned)nWblk) {
        const int idx = blockIdx.x * 256 + threadIdx.x;
        if (idx >= 6 * 16 * NKT * 64) return;
        const int lane = idx & 63;
        int r = idx >> 6;
        const int t = r % NKT; r /= NKT;
        const int g = r & 15;
        const int d = r >> 4;
        const int col  = g * 16 + (lane & 15);
        const int k0   = t * 32 + (lane >> 4) * 8;
        const float* __restrict__ W = degW + (size_t)d * KDIM * OOUT;
        unsigned short* dst = Wsw + (size_t)idx * 8;
        #pragma unroll
        for (int j = 0; j < 8; ++j) {
            const int k = k0 + j;
            dst[j] = f2bf((k < KDIM) ? W[(size_t)k * OOUT + col] : 0.f);
        }
    } else {
        const int nblk = gridDim.x - nWblk;
        size_t i = (size_t)(blockIdx.x - nWblk) * 256 + threadIdx.x;
        const size_t stride = (size_t)nblk * 256;
        const size_t total = ATH_SHORTS / 4;
        const f32x4* __restrict__ src = (const f32x4*)atoms;
        u16x4* __restrict__ dst = (u16x4*)atomsH;
        for (; i < total; i += stride) {
            f32x4 v = __builtin_nontemporal_load(&src[i]);
            u16x4 h;
            h.x = f2h(v.x); h.y = f2h(v.y); h.z = f2h(v.z); h.w = f2h(v.w);
            __builtin_nontemporal_store(h, &dst[i]);
        }
    }
}

__global__ __launch_bounds__(256)
void convert_w_kernel(const float* __restrict__ degW, unsigned short* __restrict__ Wsw,
                      int all6)
{
    const int total = (all6 ? 6 : 1) * 16 * NKT * 64;
    const int idx = blockIdx.x * 256 + threadIdx.x;
    if (idx >= total) return;
    const int lane = idx & 63;
    int r = idx >> 6;
    const int t = r % NKT; r /= NKT;
    const int g = r & 15;
    const int d = r >> 4;
    const int srcd = all6 ? d : DEG;
    const int col  = g * 16 + (lane & 15);
    const int k0   = t * 32 + (lane >> 4) * 8;
    const float* __restrict__ W = degW + (size_t)srcd * KDIM * OOUT;
    unsigned short* dst = Wsw + (size_t)idx * 8;
    #pragma unroll
    for (int j = 0; j < 8; ++j) {
        const int k = k0 + j;
        dst[j] = f2bf((k < KDIM) ? W[(size_t)k * OOUT + col] : 0.f);
    }
}

template <int MODE>
__global__ __launch_bounds__(256, 4)
void nfp_fused_kernel(const float* __restrict__ atoms, const unsigned short* __restrict__ atomsH,
                      const float* __restrict__ bonds, const int* __restrict__ edges,
                      const unsigned short* __restrict__ Wsw, const float* __restrict__ degW,
                      const float* __restrict__ bias, float* __restrict__ out)
{
    constexpr bool FP16N = (MODE == 2);
    constexpr bool ALL6  = (MODE >= 1);

    __shared__ short Afeat[MT * AS];
    __shared__ int   edg[MT * DEG];
    __shared__ int   deg_lds[MT];
    __shared__ int   degmask;

    const int tid  = threadIdx.x;
    const int lane = tid & 63;
    const int wave = tid >> 6;

    const int bid   = blockIdx.x;
    const int xcd   = bid & 7;
    const int per   = bid >> 3;
    const int batch = (per >> 5) * 8 + xcd;
    const int blk   = per & 31;
    const int row0  = batch * NATOMS + blk * MT;

    if (tid == 0) degmask = 0;
    if (tid < MT * DEG) edg[tid] = edges[row0 * DEG + tid];
    __syncthreads();
    if (tid < MT) {
        int dc = 0;
        #pragma unroll
        for (int d = 0; d < DEG; ++d) dc += (edg[tid * DEG + d] != -1) ? 1 : 0;
        deg_lds[tid] = dc;
        atomicOr(&degmask, 1 << dc);
    }

    const float* __restrict__ abase = atoms + ((size_t)batch << 10) * FIN;
    const unsigned short* __restrict__ hbase =
        FP16N ? atomsH + ((size_t)batch << 10) * FIN : atomsH;
    const int selfrow = blk * MT;
    const int mw = wave * 8;

#define GATHER_CHUNK(MB, NR)                                                          \
    {                                                                                 \
        f32x4 self[NR]; int msk[NR];                                                  \
        u16x4 nh[NR][DEG]; f32x4 nv[NR][DEG];                                         \
        _Pragma("unroll")                                                             \
        for (int r = 0; r < NR; ++r) {                                                \
            const int m = (MB) + r;                                                   \
            msk[r] = 0;                                                               \
            self[r] = __builtin_nontemporal_load(                                     \
                (const f32x4*)&abase[(size_t)(selfrow + m) * FIN + lane * 4]);        \
            _Pragma("unroll")                                                         \
            for (int d = 0; d < DEG; ++d) {                                           \
                const int e = edg[m * DEG + d];                                       \
                msk[r] |= (e >= 0) ? (1 << d) : 0;                                    \
                const int ei = (e >= 0) ? e : 0;                                      \
                if constexpr (FP16N)                                                  \
                    nh[r][d] = *(const u16x4*)&hbase[(size_t)ei * FIN + lane * 4];    \
                else                                                                  \
                    nv[r][d] = *(const f32x4*)&abase[(size_t)ei * FIN + lane * 4];    \
            }                                                                         \
        }                                                                             \
        _Pragma("unroll")                                                             \
        for (int r = 0; r < NR; ++r) {                                                \
            const int m = (MB) + r;                                                   \
            f32x4 v = self[r];                                                        \
            _Pragma("unroll")                                                         \
            for (int d = 0; d < DEG; ++d) {                                           \
                const float fl = ((msk[r] >> d) & 1) ? 1.f : 0.f;                     \
                if constexpr (FP16N) {                                                \
                    v.x += fl * h2f(nh[r][d].x); v.y += fl * h2f(nh[r][d].y);         \
                    v.z += fl * h2f(nh[r][d].z); v.w += fl * h2f(nh[r][d].w);         \
                } else {                                                              \
                    v.x += fl * nv[r][d].x; v.y += fl * nv[r][d].y;                   \
                    v.z += fl * nv[r][d].z; v.w += fl * nv[r][d].w;                   \
                }                                                                     \
            }                                                                         \
            u16x4 us;                                                                 \
            us.x = f2bf(v.x); us.y = f2bf(v.y); us.z = f2bf(v.z); us.w = f2bf(v.w);   \
            *(u16x4*)&Afeat[m * AS + lane * 4] = us;                                  \
        }                                                                             \
    }

    GATHER_CHUNK(mw + 0, 3)
    GATHER_CHUNK(mw + 3, 3)
    GATHER_CHUNK(mw + 6, 2)
#undef GATHER_CHUNK

    {
        const int mz = mw + (lane >> 3), pz = lane & 7;
        u16x4 zz = {0, 0, 0, 0};
        *(u16x4*)&Afeat[mz * AS + FIN + pz * 4] = zz;
        if (lane < 48) {
            const int r  = lane / 6;
            const int kk = lane - r * 6;
            const int m  = mw + r;
            const float* __restrict__ bb = bonds + ((size_t)(row0 + m)) * (DEG * NBF) + kk;
            const float bv = bb[0] + bb[NBF] + bb[2 * NBF] + bb[3 * NBF] + bb[4 * NBF];
            Afeat[m * AS + FIN + kk] = f2bf(bv);
        }
    }

    const unsigned short* __restrict__ Wb5 =
        Wsw + (ALL6 ? (size_t)DEG * FRAG_SHORTS : (size_t)0);
    const int fr = lane & 15;
    const int q  = lane >> 4;
    const int wn = wave * 64;

    bf16x8 b0[4];
    #pragma unroll
    for (int j = 0; j < 4; ++j)
        b0[j] = *(const bf16x8*)&Wb5[((size_t)((wave * 4 + j) * NKT) * 64 + lane) * 8];

    __syncthreads();

    auto gemm_pass = [&](const unsigned short* __restrict__ Wb, bf16x8 (&bini)[4],
                         f32x4 (&a)[2][4]) {
        bf16x8 bcur[4], bnxt[4], acur[2], anxt[2];
        #pragma unroll
        for (int j = 0; j < 4; ++j) bcur[j] = bini[j];
        #pragma unroll
        for (int i = 0; i < 2; ++i)
            acur[i] = *(const bf16x8*)&Afeat[(i * 16 + fr) * AS + q * 8];
        #pragma unroll
        for (int t = 0; t < NKT; ++t) {
            if (t + 1 < NKT) {
                #pragma unroll
                for (int j = 0; j < 4; ++j)
                    bnxt[j] = *(const bf16x8*)&Wb[((size_t)((wave * 4 + j) * NKT + t + 1) * 64 + lane) * 8];
                #pragma unroll
                for (int i = 0; i < 2; ++i)
                    anxt[i] = *(const bf16x8*)&Afeat[(i * 16 + fr) * AS + (t + 1) * 32 + q * 8];
            }
            #pragma unroll
            for (int i = 0; i < 2; ++i)
                #pragma unroll
                for (int j = 0; j < 4; ++j)
                    a[i][j] = __builtin_amdgcn_mfma_f32_16x16x32_bf16(acur[i], bcur[j], a[i][j], 0, 0, 0);
            if (t + 1 < NKT) {
                #pragma unroll
                for (int j = 0; j < 4; ++j) bcur[j] = bnxt[j];
                #pragma unroll
                for (int i = 0; i < 2; ++i) acur[i] = anxt[i];
            }
        }
    };

    auto epilogue = [&](f32x4 (&a)[2][4], int want) {
        #pragma unroll
        for (int j = 0; j < 4; ++j) {
            const int gn = wn + j * 16 + fr;
            const float bjv = bias[gn];
            #pragma unroll
            for (int i = 0; i < 2; ++i) {
                #pragma unroll
                for (int r = 0; r < 4; ++r) {
                    const int lm = i * 16 + q * 4 + r;
                    if (deg_lds[lm] == want)
                        __builtin_nontemporal_store(sigmoidf_(a[i][j][r] + bjv),
                                                    &out[((size_t)row0 + lm) * OOUT + gn]);
                }
            }
        }
    };

    f32x4 acc[2][4];
    #pragma unroll
    for (int i = 0; i < 2; ++i)
        #pragma unroll
        for (int j = 0; j < 4; ++j)
            acc[i][j] = (f32x4){0.f, 0.f, 0.f, 0.f};

    gemm_pass(Wb5, b0, acc);
    epilogue(acc, DEG);

    int dmask = degmask & 0x1F;
    if (dmask == 0) return;

    if constexpr (ALL6) {
        while (dmask) {
            const int d = __ffs(dmask) - 1;
            dmask &= dmask - 1;
            const unsigned short* __restrict__ Wd = Wsw + (size_t)d * FRAG_SHORTS;
            bf16x8 bd[4];
            #pragma unroll
            for (int j = 0; j < 4; ++j)
                bd[j] = *(const bf16x8*)&Wd[((size_t)((wave * 4 + j) * NKT) * 64 + lane) * 8];
            f32x4 a2[2][4];
            #pragma unroll
            for (int i = 0; i < 2; ++i)
                #pragma unroll
                for (int j = 0; j < 4; ++j)
                    a2[i][j] = (f32x4){0.f, 0.f, 0.f, 0.f};
            gemm_pass(Wd, bd, a2);
            epilogue(a2, d);
        }
    } else {
        for (int m = 0; m < MT; ++m) {
            const int dg = deg_lds[m];
            if (dg == DEG) continue;
            const float* __restrict__ W = degW + (size_t)dg * KDIM * OOUT;
            float s0 = 0.f, s1 = 0.f, s2 = 0.f, s3 = 0.f;
            #pragma unroll 2
            for (int k = 0; k < 260; k += 4) {
                const float w0 = W[(size_t)(k + 0) * OOUT + tid];
                const float w1 = W[(size_t)(k + 1) * OOUT + tid];
                const float w2 = W[(size_t)(k + 2) * OOUT + tid];
                const float w3 = W[(size_t)(k + 3) * OOUT + tid];
                s0 += bf2f(Afeat[m * AS + k + 0]) * w0;
                s1 += bf2f(Afeat[m * AS + k + 1]) * w1;
                s2 += bf2f(Afeat[m * AS + k + 2]) * w2;
                s3 += bf2f(Afeat[m * AS + k + 3]) * w3;
            }
            s0 += bf2f(Afeat[m * AS + 260]) * W[(size_t)260 * OOUT + tid];
            s1 += bf2f(Afeat[m * AS + 261]) * W[(size_t)261 * OOUT + tid];
            const float x = ((s0 + s1) + (s2 + s3)) + bias[tid];
            out[((size_t)row0 + m) * OOUT + tid] = sigmoidf_(x);
        }
    }
}

#define FMT  32
#define FKT  32
#define FKPAD 288
__global__ __launch_bounds__(256, 2)
void nfp_conv_fallback(const float* __restrict__ atoms, const float* __restrict__ bonds,
                       const int* __restrict__ edges, const float* __restrict__ degW,
                       const float* __restrict__ bias, float* __restrict__ out)
{
    __shared__ float feats[FMT * FKPAD];
    __shared__ float wtile[FKT * OOUT];
    __shared__ int   edg[FMT * DEG];
    __shared__ int   deg_lds[FMT];
    __shared__ int   odd_list[FMT];
    __shared__ int   odd_cnt;
    __shared__ float b_lds[OOUT];

    const int tid = threadIdx.x, bid = blockIdx.x;
    const int batch = bid >> 5, a0 = (bid & 31) * FMT;
    const size_t atom_base = (size_t)batch * NATOMS;

    b_lds[tid] = bias[tid];
    if (tid == 0) odd_cnt = 0;
    if (tid < FMT * DEG) {
        const int m = tid / DEG, d = tid % DEG;
        edg[tid] = edges[(atom_base + a0 + m) * DEG + d];
    }
    __syncthreads();
    if (tid < FMT) {
        int dc = 0;
        #pragma unroll
        for (int d = 0; d < DEG; ++d) dc += (edg[tid * DEG + d] != -1) ? 1 : 0;
        deg_lds[tid] = dc;
        if (dc != DEG) { const int idx = atomicAdd(&odd_cnt, 1); odd_list[idx] = tid; }
    }
    __syncthreads();
    {
        const int f = tid;
        for (int m = 0; m < FMT; ++m) {
            float v = atoms[(atom_base + a0 + m) * FIN + f];
            #pragma unroll
            for (int d = 0; d < DEG; ++d) {
                const int e = edg[m * DEG + d];
                if (e >= 0) v += atoms[(atom_base + e) * FIN + f];
            }
            feats[m * FKPAD + f] = v;
        }
        #pragma unroll
        for (int t = 0; t < 4; ++t) {
            const int idx = t * 256 + tid;
            const int m = idx >> 5, kk = idx & 31;
            float v = 0.f;
            if (kk < NBF) {
                const size_t bb = (atom_base + a0 + m) * (size_t)(DEG * NBF);
                #pragma unroll
                for (int d = 0; d < DEG; ++d) v += bonds[bb + d * NBF + kk];
            }
            feats[m * FKPAD + FIN + kk] = v;
        }
    }
    const float* __restrict__ W5 = degW + (size_t)DEG * KDIM * OOUT;
    float acc[4][8];
    #pragma unroll
    for (int i = 0; i < 4; ++i)
        #pragma unroll
        for (int j = 0; j < 8; ++j) acc[i][j] = 0.f;
    const int tx = tid & 31, ty = tid >> 5;
    for (int kt = 0; kt < FKPAD; kt += FKT) {
        __syncthreads();
        #pragma unroll
        for (int t = 0; t < FKT; ++t) {
            const int k = kt + t;
            wtile[t * OOUT + tid] = (k < KDIM) ? W5[(size_t)k * OOUT + tid] : 0.f;
        }
        __syncthreads();
        #pragma unroll 4
        for (int r = 0; r < FKT; ++r) {
            float a_frag[4];
            #pragma unroll
            for (int i = 0; i < 4; ++i) a_frag[i] = feats[(ty * 4 + i) * FKPAD + kt + r];
            float w_frag[8];
            #pragma unroll
            for (int j = 0; j < 8; ++j) w_frag[j] = wtile[r * OOUT + tx + j * 32];
            #pragma unroll
            for (int i = 0; i < 4; ++i)
                #pragma unroll
                for (int j = 0; j < 8; ++j) acc[i][j] += a_frag[i] * w_frag[j];
        }
    }
    #pragma unroll
    for (int i = 0; i < 4; ++i) {
        const int m = ty * 4 + i;
        if (deg_lds[m] == DEG) {
            const size_t row = (atom_base + a0 + m) * (size_t)OOUT;
            #pragma unroll
            for (int j = 0; j < 8; ++j) {
                const int o = tx + j * 32;
                out[row + o] = sigmoidf_(acc[i][j] + b_lds[o]);
            }
        }
    }
    const int ocnt = odd_cnt;
    for (int i = 0; i < ocnt; ++i) {
        const int m = odd_list[i], d = deg_lds[m];
        const float* __restrict__ W = degW + (size_t)d * KDIM * OOUT;
        float a2 = 0.f;
        for (int k = 0; k < KDIM; ++k) a2 += feats[m * FKPAD + k] * W[(size_t)k * OOUT + tid];
        const size_t row = (atom_base + a0 + m) * (size_t)OOUT;
        out[row + tid] = sigmoidf_(a2 + b_lds[tid]);
    }
}

// ---------------------------------------------------------------------------
extern "C" void kernel_launch(void* const* d_in, const int* in_sizes, int n_in,
                              void* d_out, int out_size, void* d_ws, size_t ws_size,
                              hipStream_t stream) {
    const float* atoms = (const float*)d_in[0];
    const float* bonds = (const float*)d_in[1];
    const int*   edges = (const int*)d_in[2];
    const float* degW  = (const float*)d_in[3];
    const float* bias  = (const float*)d_in[4];
    float* out = (float*)d_out;

    const size_t WSW_ONE = (size_t)FRAG_SHORTS * 2;      // 147,456 B
    const size_t WSW_ALL = (size_t)6 * FRAG_SHORTS * 2;  // 884,736 B
    const size_t ATH_B   = ATH_SHORTS * 2;               // 33,554,432 B
    const size_t FEATS_B = (size_t)MROWS * AS * 2;       // 38,797,312 B
    const size_t NEED_SPLIT = WSW_ALL + FEATS_B + (size_t)MROWS;  // 39,747,584 B

    if (ws_size >= NEED_SPLIT) {
        // Split path: featurize -> register-pipelined GEMM -> odd-row fixup.
        unsigned short* Wsw   = (unsigned short*)d_ws;
        unsigned short* feats = (unsigned short*)((char*)d_ws + WSW_ALL);
        unsigned char*  degB  = (unsigned char*)((char*)d_ws + WSW_ALL + FEATS_B);
        prep_kernel<<<NWBLK + MROWS / (4 * 8), 256, 0, stream>>>(   // 216 + 2048
            degW, Wsw, atoms, bonds, edges, feats, degB);
        nfp_gemm_kernel<<<MROWS / BM, 256, 0, stream>>>(            // 2048 blocks
            feats, Wsw + (size_t)DEG * FRAG_SHORTS, bias, out);
        nfp_fixup_kernel<<<MROWS / 256, 256, 0, stream>>>(          // 256 blocks
            feats, degB, degW, bias, out);
    } else if (ws_size >= WSW_ALL + ATH_B) {
        unsigned short* Wsw    = (unsigned short*)d_ws;
        unsigned short* atomsH = (unsigned short*)((char*)d_ws + WSW_ALL);
        const int nWblk = (6 * 16 * NKT * 64 + 255) / 256;
        convert_pre_kernel<<<nWblk + 2048, 256, 0, stream>>>(degW, Wsw, atoms, atomsH, nWblk);
        nfp_fused_kernel<2><<<MROWS / MT, 256, 0, stream>>>(
            atoms, atomsH, bonds, edges, Wsw, degW, bias, out);
    } else if (ws_size >= WSW_ALL) {
        unsigned short* Wsw = (unsigned short*)d_ws;
        convert_w_kernel<<<(6 * 16 * NKT * 64 + 255) / 256, 256, 0, stream>>>(degW, Wsw, 1);
        nfp_fused_kernel<1><<<MROWS / MT, 256, 0, stream>>>(
            atoms, nullptr, bonds, edges, Wsw, degW, bias, out);
    } else if (ws_size >= WSW_ONE) {
        unsigned short* Wsw = (unsigned short*)d_ws;
        convert_w_kernel<<<(16 * NKT * 64 + 255) / 256, 256, 0, stream>>>(degW, Wsw, 0);
        nfp_fused_kernel<0><<<MROWS / MT, 256, 0, stream>>>(
            atoms, nullptr, bonds, edges, Wsw, degW, bias, out);
    } else {
        nfp_conv_fallback<<<BATCH * (NATOMS / FMT), 256, 0, stream>>>(
            atoms, bonds, edges, degW, bias, out);
    }
}

// Round 7
// 240.916 us; speedup vs baseline: 1.2199x; 1.0056x over previous
//
#include <hip/hip_runtime.h>
#include <hip/hip_fp16.h>
#include <cstdint>

// Problem constants (fixed by the reference)
#define BATCH  64
#define NATOMS 1024
#define DEG    5
#define FIN    256
#define OOUT   256
#define NBF    6
#define KDIM   262          // FIN + NBF
#define NKT    9            // k-tiles of 32 (K padded to 288)
#define MROWS  (BATCH * NATOMS)   // 65536
#define MT     32           // atom rows per block (legacy fused kernel)
#define AS     296          // feats row stride in shorts (592B, 16B-aligned)

#define FRAG_SHORTS (16 * NKT * 64 * 8)   // 73,728 shorts (147,456 B) per degree
#define ATH_SHORTS  ((size_t)MROWS * FIN) // fp16 atoms cache (legacy path)
#define NWBLK 216                         // 6*16*9*64 / 256 W-swizzle blocks (216%8==0:
                                          // featurize blocks keep XCD parity)

typedef __attribute__((ext_vector_type(8))) short bf16x8;          // MFMA A/B frag (4 VGPR)
typedef __attribute__((ext_vector_type(4))) float f32x4;           // MFMA C/D frag
typedef __attribute__((ext_vector_type(4))) unsigned short u16x4;  // bf16/fp16 quad

__device__ __forceinline__ unsigned short f2bf(float x) {
    unsigned u = __float_as_uint(x);
    u += 0x7fff + ((u >> 16) & 1);          // round-to-nearest-even
    return (unsigned short)(u >> 16);
}
__device__ __forceinline__ float bf2f(unsigned short h) {
    return __uint_as_float(((unsigned)h) << 16);
}
__device__ __forceinline__ float sigmoidf_(float x) {
    return 1.f / (1.f + __expf(-x));
}
__device__ __forceinline__ unsigned short f2h(float x) {
    return __half_as_ushort(__float2half(x));
}
__device__ __forceinline__ float h2f(unsigned short u) {
    return __half2float(__ushort_as_half(u));
}

// ---------------------------------------------------------------------------
// SPLIT PATH kernel 1 (R7): prep = W-swizzle (216 blocks) + featurize (2048).
// R7 changes vs R6 (both target the 196 MB FETCH / 42%-BW counters):
//  (a) XCD-aware row mapping: featurize block fb -> XCD fb&7 owns batches
//      [8*(fb&7), 8*(fb&7)+8). Per-XCD neighbor working set 64 MB -> 8 MB,
//      so atom-row re-reads hit the local L2 instead of re-fetching HBM.
//  (b) all 6 row-loads (self + 5 neighbors) issued into registers BEFORE any
//      accumulate: breaks the load->add serial chain (VGPR 24 showed nothing
//      was in flight). 24 payload VGPRs, still within the 64-reg/8-wave cap.
// ---------------------------------------------------------------------------
__global__ __launch_bounds__(256, 8)
void prep_kernel(const float* __restrict__ degW, unsigned short* __restrict__ Wsw,
                 const float* __restrict__ atoms, const float* __restrict__ bonds,
                 const int* __restrict__ edges,
                 unsigned short* __restrict__ feats, unsigned char* __restrict__ degB)
{
    if (blockIdx.x < NWBLK) {
        const int idx = blockIdx.x * 256 + threadIdx.x;   // < 6*16*9*64 = 55296 always
        const int lane = idx & 63;
        int r = idx >> 6;
        const int t = r % NKT; r /= NKT;
        const int g = r & 15;
        const int d = r >> 4;
        const int col  = g * 16 + (lane & 15);
        const int k0   = t * 32 + (lane >> 4) * 8;
        const float* __restrict__ W = degW + (size_t)d * KDIM * OOUT;
        unsigned short* dst = Wsw + (size_t)idx * 8;
        #pragma unroll
        for (int j = 0; j < 8; ++j) {
            const int k = k0 + j;
            dst[j] = f2bf((k < KDIM) ? W[(size_t)k * OOUT + col] : 0.f);
        }
        return;
    }

    // ---- featurize: XCD-chunked row ownership ----
    const int fb   = blockIdx.x - NWBLK;          // 0..2047; dispatched to XCD fb&7
    const int xcd  = fb & 7;
    const int per  = fb >> 3;                     // 0..255 within the XCD
    const int wid  = (xcd * 256 + per) * 4 + ((int)threadIdx.x >> 6);  // 0..8191
    const int lane = threadIdx.x & 63;
    const int r0   = wid * 8;                     // XCD x owns rows [x*8192, x*8192+8192)

    int ev[8];
    #pragma unroll
    for (int rr = 0; rr < 8; ++rr)
        ev[rr] = (lane < DEG) ? edges[(size_t)(r0 + rr) * DEG + lane] : -1;

    for (int rr = 0; rr < 8; ++rr) {
        const int row = r0 + rr;
        const float* __restrict__ abase = atoms + ((size_t)(row >> 10) << 10) * FIN;
        const int dg = (int)__popcll(__ballot(ev[rr] >= 0));

        // broadcast the 5 edge ids first, then issue ALL 6 loads back-to-back
        int ed[DEG];
        #pragma unroll
        for (int d = 0; d < DEG; ++d) ed[d] = __shfl(ev[rr], d);

        f32x4 v = *(const f32x4*)&atoms[(size_t)row * FIN + lane * 4];
        f32x4 nv[DEG];
        #pragma unroll
        for (int d = 0; d < DEG; ++d)
            nv[d] = *(const f32x4*)&abase[(size_t)((ed[d] >= 0) ? ed[d] : 0) * FIN + lane * 4];

        #pragma unroll
        for (int d = 0; d < DEG; ++d) {
            const float fl = (ed[d] >= 0) ? 1.f : 0.f;
            v.x += fl * nv[d].x; v.y += fl * nv[d].y;
            v.z += fl * nv[d].z; v.w += fl * nv[d].w;
        }
        u16x4 us;
        us.x = f2bf(v.x); us.y = f2bf(v.y); us.z = f2bf(v.z); us.w = f2bf(v.w);
        *(u16x4*)&feats[(size_t)row * AS + lane * 4] = us;

        float bx = (lane < DEG * NBF) ? bonds[(size_t)row * (DEG * NBF) + lane] : 0.f;
        const int kk = (lane < NBF) ? lane : 0;
        float bs = 0.f;
        #pragma unroll
        for (int p = 0; p < DEG; ++p) bs += __shfl(bx, kk + NBF * p);
        if (lane < NBF)       feats[(size_t)row * AS + FIN + lane] = f2bf(bs);
        else if (lane < 32)   feats[(size_t)row * AS + FIN + lane] = 0;   // k=262..287 must be 0
        if (lane == 0)        degB[row] = (unsigned char)dg;
    }
}

// ---------------------------------------------------------------------------
// SPLIT PATH kernel 2 (unchanged from R6): streaming MFMA GEMM, register-
// pipelined, LDS-transposed coalesced epilogue.
// ---------------------------------------------------------------------------
#define BM 32
__global__ __launch_bounds__(256, 4)
void nfp_gemm_kernel(const unsigned short* __restrict__ feats,
                     const unsigned short* __restrict__ Wsw5,
                     const float* __restrict__ bias, float* __restrict__ out)
{
    __shared__ float Ct[BM * OOUT];   // 32,768 B

    const int tid  = threadIdx.x;
    const int lane = tid & 63;
    const int wave = tid >> 6;
    const int row0 = blockIdx.x * BM;
    const int fr   = lane & 15;
    const int q    = lane >> 4;
    const int wn   = wave * 64;

    f32x4 acc[2][4];
    #pragma unroll
    for (int i = 0; i < 2; ++i)
        #pragma unroll
        for (int j = 0; j < 4; ++j)
            acc[i][j] = (f32x4){0.f, 0.f, 0.f, 0.f};

    const unsigned short* __restrict__ A0 = feats + (size_t)(row0 + fr) * AS + q * 8;
    const unsigned short* __restrict__ A1 = A0 + 16 * AS;
    const unsigned short* __restrict__ B0 = Wsw5 + ((size_t)(wave * 4) * NKT * 64 + lane) * 8;

    auto ldb = [&](int j, int t) {
        return *(const bf16x8*)&B0[(size_t)((j * NKT + t) * 64) * 8];
    };

    bf16x8 bc[4], bn[4], ac[2], an[2];
    #pragma unroll
    for (int j = 0; j < 4; ++j) bc[j] = ldb(j, 0);
    ac[0] = *(const bf16x8*)&A0[0];
    ac[1] = *(const bf16x8*)&A1[0];

    #pragma unroll
    for (int t = 0; t < NKT; ++t) {
        if (t + 1 < NKT) {                         // prefetch next k-tile
            #pragma unroll
            for (int j = 0; j < 4; ++j) bn[j] = ldb(j, t + 1);
            an[0] = *(const bf16x8*)&A0[(t + 1) * 32];
            an[1] = *(const bf16x8*)&A1[(t + 1) * 32];
        }
        #pragma unroll
        for (int i = 0; i < 2; ++i)
            #pragma unroll
            for (int j = 0; j < 4; ++j)
                acc[i][j] = __builtin_amdgcn_mfma_f32_16x16x32_bf16(ac[i], bc[j], acc[i][j], 0, 0, 0);
        if (t + 1 < NKT) {
            #pragma unroll
            for (int j = 0; j < 4; ++j) bc[j] = bn[j];
            ac[0] = an[0]; ac[1] = an[1];
        }
    }

    // ---- epilogue 1: bias+sigmoid -> swizzled LDS ----
    float bj[4];
    #pragma unroll
    for (int j = 0; j < 4; ++j) bj[j] = bias[wn + j * 16 + fr];

    #pragma unroll
    for (int i = 0; i < 2; ++i) {
        #pragma unroll
        for (int r = 0; r < 4; ++r) {
            const int lm = i * 16 + q * 4 + r;
            const int sw = ((lm >> 2) & 3) << 4;
            #pragma unroll
            for (int j = 0; j < 4; ++j)
                Ct[lm * OOUT + ((wn + j * 16 + fr) ^ sw)] = sigmoidf_(acc[i][j][r] + bj[j]);
        }
    }
    __syncthreads();

    // ---- epilogue 2: coalesced full-line streaming stores ----
    const f32x4* __restrict__ src = (const f32x4*)Ct;
    f32x4* __restrict__ dst = (f32x4*)(out + (size_t)row0 * OOUT);
    #pragma unroll
    for (int c = 0; c < 8; ++c) {
        const int v   = c * 256 + tid;
        const int row = v >> 6;
        const int c4  = v & 63;
        const int c4s = c4 ^ (((row >> 2) & 3) << 2);
        __builtin_nontemporal_store(src[row * 64 + c4s], &dst[v]);
    }
}

// ---------------------------------------------------------------------------
// SPLIT PATH kernel 3: odd-degree fixup (unchanged).
// ---------------------------------------------------------------------------
__global__ __launch_bounds__(256, 4)
void nfp_fixup_kernel(const unsigned short* __restrict__ feats,
                      const unsigned char* __restrict__ degB,
                      const float* __restrict__ degW, const float* __restrict__ bias,
                      float* __restrict__ out)
{
    __shared__ int list[256];
    __shared__ int cnt;
    const int tid = threadIdx.x;
    if (tid == 0) cnt = 0;
    __syncthreads();
    const int r = blockIdx.x * 256 + tid;
    if (degB[r] != DEG) { const int i = atomicAdd(&cnt, 1); list[i] = r; }
    __syncthreads();
    const int n = cnt;
    for (int i = 0; i < n; ++i) {
        const int row = list[i];
        const int d   = degB[row];
        const float* __restrict__ W = degW + (size_t)d * KDIM * OOUT + tid;
        const unsigned short* __restrict__ fv = feats + (size_t)row * AS;
        float s0 = 0.f, s1 = 0.f;
        #pragma unroll 4
        for (int k = 0; k < KDIM; k += 2) {                 // KDIM=262 even
            s0 += bf2f(fv[k])     * W[(size_t)k * OOUT];
            s1 += bf2f(fv[k + 1]) * W[(size_t)(k + 1) * OOUT];
        }
        out[(size_t)row * OOUT + tid] = sigmoidf_(s0 + s1 + bias[tid]);
    }
}

// ===========================================================================
// Legacy paths below (kept verified as workspace-size fallbacks)
// ===========================================================================

__global__ __launch_bounds__(256)
void convert_pre_kernel(const float* __restrict__ degW, unsigned short* __restrict__ Wsw,
                        const float* __restrict__ atoms, unsigned short* __restrict__ atomsH,
                        int nWblk)
{
    if (blockIdx.x < (unsigned)nWblk) {
        const int idx = blockIdx.x * 256 + threadIdx.x;
        if (idx >= 6 * 16 * NKT * 64) return;
        const int lane = idx & 63;
        int r = idx >> 6;
        const int t = r % NKT; r /= NKT;
        const int g = r & 15;
        const int d = r >> 4;
        const int col  = g * 16 + (lane & 15);
        const int k0   = t * 32 + (lane >> 4) * 8;
        const float* __restrict__ W = degW + (size_t)d * KDIM * OOUT;
        unsigned short* dst = Wsw + (size_t)idx * 8;
        #pragma unroll
        for (int j = 0; j < 8; ++j) {
            const int k = k0 + j;
            dst[j] = f2bf((k < KDIM) ? W[(size_t)k * OOUT + col] : 0.f);
        }
    } else {
        const int nblk = gridDim.x - nWblk;
        size_t i = (size_t)(blockIdx.x - nWblk) * 256 + threadIdx.x;
        const size_t stride = (size_t)nblk * 256;
        const size_t total = ATH_SHORTS / 4;
        const f32x4* __restrict__ src = (const f32x4*)atoms;
        u16x4* __restrict__ dst = (u16x4*)atomsH;
        for (; i < total; i += stride) {
            f32x4 v = __builtin_nontemporal_load(&src[i]);
            u16x4 h;
            h.x = f2h(v.x); h.y = f2h(v.y); h.z = f2h(v.z); h.w = f2h(v.w);
            __builtin_nontemporal_store(h, &dst[i]);
        }
    }
}

__global__ __launch_bounds__(256)
void convert_w_kernel(const float* __restrict__ degW, unsigned short* __restrict__ Wsw,
                      int all6)
{
    const int total = (all6 ? 6 : 1) * 16 * NKT * 64;
    const int idx = blockIdx.x * 256 + threadIdx.x;
    if (idx >= total) return;
    const int lane = idx & 63;
    int r = idx >> 6;
    const int t = r % NKT; r /= NKT;
    const int g = r & 15;
    const int d = r >> 4;
    const int srcd = all6 ? d : DEG;
    const int col  = g * 16 + (lane & 15);
    const int k0   = t * 32 + (lane >> 4) * 8;
    const float* __restrict__ W = degW + (size_t)srcd * KDIM * OOUT;
    unsigned short* dst = Wsw + (size_t)idx * 8;
    #pragma unroll
    for (int j = 0; j < 8; ++j) {
        const int k = k0 + j;
        dst[j] = f2bf((k < KDIM) ? W[(size_t)k * OOUT + col] : 0.f);
    }
}

template <int MODE>
__global__ __launch_bounds__(256, 4)
void nfp_fused_kernel(const float* __restrict__ atoms, const unsigned short* __restrict__ atomsH,
                      const float* __restrict__ bonds, const int* __restrict__ edges,
                      const unsigned short* __restrict__ Wsw, const float* __restrict__ degW,
                      const float* __restrict__ bias, float* __restrict__ out)
{
    constexpr bool FP16N = (MODE == 2);
    constexpr bool ALL6  = (MODE >= 1);

    __shared__ short Afeat[MT * AS];
    __shared__ int   edg[MT * DEG];
    __shared__ int   deg_lds[MT];
    __shared__ int   degmask;

    const int tid  = threadIdx.x;
    const int lane = tid & 63;
    const int wave = tid >> 6;

    const int bid   = blockIdx.x;
    const int xcd   = bid & 7;
    const int per   = bid >> 3;
    const int batch = (per >> 5) * 8 + xcd;
    const int blk   = per & 31;
    const int row0  = batch * NATOMS + blk * MT;

    if (tid == 0) degmask = 0;
    if (tid < MT * DEG) edg[tid] = edges[row0 * DEG + tid];
    __syncthreads();
    if (tid < MT) {
        int dc = 0;
        #pragma unroll
        for (int d = 0; d < DEG; ++d) dc += (edg[tid * DEG + d] != -1) ? 1 : 0;
        deg_lds[tid] = dc;
        atomicOr(&degmask, 1 << dc);
    }

    const float* __restrict__ abase = atoms + ((size_t)batch << 10) * FIN;
    const unsigned short* __restrict__ hbase =
        FP16N ? atomsH + ((size_t)batch << 10) * FIN : atomsH;
    const int selfrow = blk * MT;
    const int mw = wave * 8;

#define GATHER_CHUNK(MB, NR)                                                          \
    {                                                                                 \
        f32x4 self[NR]; int msk[NR];                                                  \
        u16x4 nh[NR][DEG]; f32x4 nv[NR][DEG];                                         \
        _Pragma("unroll")                                                             \
        for (int r = 0; r < NR; ++r) {                                                \
            const int m = (MB) + r;                                                   \
            msk[r] = 0;                                                               \
            self[r] = __builtin_nontemporal_load(                                     \
                (const f32x4*)&abase[(size_t)(selfrow + m) * FIN + lane * 4]);        \
            _Pragma("unroll")                                                         \
            for (int d = 0; d < DEG; ++d) {                                           \
                const int e = edg[m * DEG + d];                                       \
                msk[r] |= (e >= 0) ? (1 << d) : 0;                                    \
                const int ei = (e >= 0) ? e : 0;                                      \
                if constexpr (FP16N)                                                  \
                    nh[r][d] = *(const u16x4*)&hbase[(size_t)ei * FIN + lane * 4];    \
                else                                                                  \
                    nv[r][d] = *(const f32x4*)&abase[(size_t)ei * FIN + lane * 4];    \
            }                                                                         \
        }                                                                             \
        _Pragma("unroll")                                                             \
        for (int r = 0; r < NR; ++r) {                                                \
            const int m = (MB) + r;                                                   \
            f32x4 v = self[r];                                                        \
            _Pragma("unroll")                                                         \
            for (int d = 0; d < DEG; ++d) {                                           \
                const float fl = ((msk[r] >> d) & 1) ? 1.f : 0.f;                     \
                if constexpr (FP16N) {                                                \
                    v.x += fl * h2f(nh[r][d].x); v.y += fl * h2f(nh[r][d].y);         \
                    v.z += fl * h2f(nh[r][d].z); v.w += fl * h2f(nh[r][d].w);         \
                } else {                                                              \
                    v.x += fl * nv[r][d].x; v.y += fl * nv[r][d].y;                   \
                    v.z += fl * nv[r][d].z; v.w += fl * nv[r][d].w;                   \
                }                                                                     \
            }                                                                         \
            u16x4 us;                                                                 \
            us.x = f2bf(v.x); us.y = f2bf(v.y); us.z = f2bf(v.z); us.w = f2bf(v.w);   \
            *(u16x4*)&Afeat[m * AS + lane * 4] = us;                                  \
        }                                                                             \
    }

    GATHER_CHUNK(mw + 0, 3)
    GATHER_CHUNK(mw + 3, 3)
    GATHER_CHUNK(mw + 6, 2)
#undef GATHER_CHUNK

    {
        const int mz = mw + (lane >> 3), pz = lane & 7;
        u16x4 zz = {0, 0, 0, 0};
        *(u16x4*)&Afeat[mz * AS + FIN + pz * 4] = zz;
        if (lane < 48) {
            const int r  = lane / 6;
            const int kk = lane - r * 6;
            const int m  = mw + r;
            const float* __restrict__ bb = bonds + ((size_t)(row0 + m)) * (DEG * NBF) + kk;
            const float bv = bb[0] + bb[NBF] + bb[2 * NBF] + bb[3 * NBF] + bb[4 * NBF];
            Afeat[m * AS + FIN + kk] = f2bf(bv);
        }
    }

    const unsigned short* __restrict__ Wb5 =
        Wsw + (ALL6 ? (size_t)DEG * FRAG_SHORTS : (size_t)0);
    const int fr = lane & 15;
    const int q  = lane >> 4;
    const int wn = wave * 64;

    bf16x8 b0[4];
    #pragma unroll
    for (int j = 0; j < 4; ++j)
        b0[j] = *(const bf16x8*)&Wb5[((size_t)((wave * 4 + j) * NKT) * 64 + lane) * 8];

    __syncthreads();

    auto gemm_pass = [&](const unsigned short* __restrict__ Wb, bf16x8 (&bini)[4],
                         f32x4 (&a)[2][4]) {
        bf16x8 bcur[4], bnxt[4], acur[2], anxt[2];
        #pragma unroll
        for (int j = 0; j < 4; ++j) bcur[j] = bini[j];
        #pragma unroll
        for (int i = 0; i < 2; ++i)
            acur[i] = *(const bf16x8*)&Afeat[(i * 16 + fr) * AS + q * 8];
        #pragma unroll
        for (int t = 0; t < NKT; ++t) {
            if (t + 1 < NKT) {
                #pragma unroll
                for (int j = 0; j < 4; ++j)
                    bnxt[j] = *(const bf16x8*)&Wb[((size_t)((wave * 4 + j) * NKT + t + 1) * 64 + lane) * 8];
                #pragma unroll
                for (int i = 0; i < 2; ++i)
                    anxt[i] = *(const bf16x8*)&Afeat[(i * 16 + fr) * AS + (t + 1) * 32 + q * 8];
            }
            #pragma unroll
            for (int i = 0; i < 2; ++i)
                #pragma unroll
                for (int j = 0; j < 4; ++j)
                    a[i][j] = __builtin_amdgcn_mfma_f32_16x16x32_bf16(acur[i], bcur[j], a[i][j], 0, 0, 0);
            if (t + 1 < NKT) {
                #pragma unroll
                for (int j = 0; j < 4; ++j) bcur[j] = bnxt[j];
                #pragma unroll
                for (int i = 0; i < 2; ++i) acur[i] = anxt[i];
            }
        }
    };

    auto epilogue = [&](f32x4 (&a)[2][4], int want) {
        #pragma unroll
        for (int j = 0; j < 4; ++j) {
            const int gn = wn + j * 16 + fr;
            const float bjv = bias[gn];
            #pragma unroll
            for (int i = 0; i < 2; ++i) {
                #pragma unroll
                for (int r = 0; r < 4; ++r) {
                    const int lm = i * 16 + q * 4 + r;
                    if (deg_lds[lm] == want)
                        __builtin_nontemporal_store(sigmoidf_(a[i][j][r] + bjv),
                                                    &out[((size_t)row0 + lm) * OOUT + gn]);
                }
            }
        }
    };

    f32x4 acc[2][4];
    #pragma unroll
    for (int i = 0; i < 2; ++i)
        #pragma unroll
        for (int j = 0; j < 4; ++j)
            acc[i][j] = (f32x4){0.f, 0.f, 0.f, 0.f};

    gemm_pass(Wb5, b0, acc);
    epilogue(acc, DEG);

    int dmask = degmask & 0x1F;
    if (dmask == 0) return;

    if constexpr (ALL6) {
        while (dmask) {
            const int d = __ffs(dmask) - 1;
            dmask &= dmask - 1;
            const unsigned short* __restrict__ Wd = Wsw + (size_t)d * FRAG_SHORTS;
            bf16x8 bd[4];
            #pragma unroll
            for (int j = 0; j < 4; ++j)
                bd[j] = *(const bf16x8*)&Wd[((size_t)((wave * 4 + j) * NKT) * 64 + lane) * 8];
            f32x4 a2[2][4];
            #pragma unroll
            for (int i = 0; i < 2; ++i)
                #pragma unroll
                for (int j = 0; j < 4; ++j)
                    a2[i][j] = (f32x4){0.f, 0.f, 0.f, 0.f};
            gemm_pass(Wd, bd, a2);
            epilogue(a2, d);
        }
    } else {
        for (int m = 0; m < MT; ++m) {
            const int dg = deg_lds[m];
            if (dg == DEG) continue;
            const float* __restrict__ W = degW + (size_t)dg * KDIM * OOUT;
            float s0 = 0.f, s1 = 0.f, s2 = 0.f, s3 = 0.f;
            #pragma unroll 2
            for (int k = 0; k < 260; k += 4) {
                const float w0 = W[(size_t)(k + 0) * OOUT + tid];
                const float w1 = W[(size_t)(k + 1) * OOUT + tid];
                const float w2 = W[(size_t)(k + 2) * OOUT + tid];
                const float w3 = W[(size_t)(k + 3) * OOUT + tid];
                s0 += bf2f(Afeat[m * AS + k + 0]) * w0;
                s1 += bf2f(Afeat[m * AS + k + 1]) * w1;
                s2 += bf2f(Afeat[m * AS + k + 2]) * w2;
                s3 += bf2f(Afeat[m * AS + k + 3]) * w3;
            }
            s0 += bf2f(Afeat[m * AS + 260]) * W[(size_t)260 * OOUT + tid];
            s1 += bf2f(Afeat[m * AS + 261]) * W[(size_t)261 * OOUT + tid];
            const float x = ((s0 + s1) + (s2 + s3)) + bias[tid];
            out[((size_t)row0 + m) * OOUT + tid] = sigmoidf_(x);
        }
    }
}

#define FMT  32
#define FKT  32
#define FKPAD 288
__global__ __launch_bounds__(256, 2)
void nfp_conv_fallback(const float* __restrict__ atoms, const float* __restrict__ bonds,
                       const int* __restrict__ edges, const float* __restrict__ degW,
                       const float* __restrict__ bias, float* __restrict__ out)
{
    __shared__ float feats[FMT * FKPAD];
    __shared__ float wtile[FKT * OOUT];
    __shared__ int   edg[FMT * DEG];
    __shared__ int   deg_lds[FMT];
    __shared__ int   odd_list[FMT];
    __shared__ int   odd_cnt;
    __shared__ float b_lds[OOUT];

    const int tid = threadIdx.x, bid = blockIdx.x;
    const int batch = bid >> 5, a0 = (bid & 31) * FMT;
    const size_t atom_base = (size_t)batch * NATOMS;

    b_lds[tid] = bias[tid];
    if (tid == 0) odd_cnt = 0;
    if (tid < FMT * DEG) {
        const int m = tid / DEG, d = tid % DEG;
        edg[tid] = edges[(atom_base + a0 + m) * DEG + d];
    }
    __syncthreads();
    if (tid < FMT) {
        int dc = 0;
        #pragma unroll
        for (int d = 0; d < DEG; ++d) dc += (edg[tid * DEG + d] != -1) ? 1 : 0;
        deg_lds[tid] = dc;
        if (dc != DEG) { const int idx = atomicAdd(&odd_cnt, 1); odd_list[idx] = tid; }
    }
    __syncthreads();
    {
        const int f = tid;
        for (int m = 0; m < FMT; ++m) {
            float v = atoms[(atom_base + a0 + m) * FIN + f];
            #pragma unroll
            for (int d = 0; d < DEG; ++d) {
                const int e = edg[m * DEG + d];
                if (e >= 0) v += atoms[(atom_base + e) * FIN + f];
            }
            feats[m * FKPAD + f] = v;
        }
        #pragma unroll
        for (int t = 0; t < 4; ++t) {
            const int idx = t * 256 + tid;
            const int m = idx >> 5, kk = idx & 31;
            float v = 0.f;
            if (kk < NBF) {
                const size_t bb = (atom_base + a0 + m) * (size_t)(DEG * NBF);
                #pragma unroll
                for (int d = 0; d < DEG; ++d) v += bonds[bb + d * NBF + kk];
            }
            feats[m * FKPAD + FIN + kk] = v;
        }
    }
    const float* __restrict__ W5 = degW + (size_t)DEG * KDIM * OOUT;
    float acc[4][8];
    #pragma unroll
    for (int i = 0; i < 4; ++i)
        #pragma unroll
        for (int j = 0; j < 8; ++j) acc[i][j] = 0.f;
    const int tx = tid & 31, ty = tid >> 5;
    for (int kt = 0; kt < FKPAD; kt += FKT) {
        __syncthreads();
        #pragma unroll
        for (int t = 0; t < FKT; ++t) {
            const int k = kt + t;
            wtile[t * OOUT + tid] = (k < KDIM) ? W5[(size_t)k * OOUT + tid] : 0.f;
        }
        __syncthreads();
        #pragma unroll 4
        for (int r = 0; r < FKT; ++r) {
            float a_frag[4];
            #pragma unroll
            for (int i = 0; i < 4; ++i) a_frag[i] = feats[(ty * 4 + i) * FKPAD + kt + r];
            float w_frag[8];
            #pragma unroll
            for (int j = 0; j < 8; ++j) w_frag[j] = wtile[r * OOUT + tx + j * 32];
            #pragma unroll
            for (int i = 0; i < 4; ++i)
                #pragma unroll
                for (int j = 0; j < 8; ++j) acc[i][j] += a_frag[i] * w_frag[j];
        }
    }
    #pragma unroll
    for (int i = 0; i < 4; ++i) {
        const int m = ty * 4 + i;
        if (deg_lds[m] == DEG) {
            const size_t row = (atom_base + a0 + m) * (size_t)OOUT;
            #pragma unroll
            for (int j = 0; j < 8; ++j) {
                const int o = tx + j * 32;
                out[row + o] = sigmoidf_(acc[i][j] + b_lds[o]);
            }
        }
    }
    const int ocnt = odd_cnt;
    for (int i = 0; i < ocnt; ++i) {
        const int m = odd_list[i], d = deg_lds[m];
        const float* __restrict__ W = degW + (size_t)d * KDIM * OOUT;
        float a2 = 0.f;
        for (int k = 0; k < KDIM; ++k) a2 += feats[m * FKPAD + k] * W[(size_t)k * OOUT + tid];
        const size_t row = (atom_base + a0 + m) * (size_t)OOUT;
        out[row + tid] = sigmoidf_(a2 + b_lds[tid]);
    }
}

// ---------------------------------------------------------------------------
extern "C" void kernel_launch(void* const* d_in, const int* in_sizes, int n_in,
                              void* d_out, int out_size, void* d_ws, size_t ws_size,
                              hipStream_t stream) {
    const float* atoms = (const float*)d_in[0];
    const float* bonds = (const float*)d_in[1];
    const int*   edges = (const int*)d_in[2];
    const float* degW  = (const float*)d_in[3];
    const float* bias  = (const float*)d_in[4];
    float* out = (float*)d_out;

    const size_t WSW_ONE = (size_t)FRAG_SHORTS * 2;      // 147,456 B
    const size_t WSW_ALL = (size_t)6 * FRAG_SHORTS * 2;  // 884,736 B
    const size_t ATH_B   = ATH_SHORTS * 2;               // 33,554,432 B
    const size_t FEATS_B = (size_t)MROWS * AS * 2;       // 38,797,312 B
    const size_t NEED_SPLIT = WSW_ALL + FEATS_B + (size_t)MROWS;  // 39,747,584 B

    if (ws_size >= NEED_SPLIT) {
        // Split path: XCD-local featurize -> register-pipelined GEMM -> fixup.
        unsigned short* Wsw   = (unsigned short*)d_ws;
        unsigned short* feats = (unsigned short*)((char*)d_ws + WSW_ALL);
        unsigned char*  degB  = (unsigned char*)((char*)d_ws + WSW_ALL + FEATS_B);
        prep_kernel<<<NWBLK + MROWS / (4 * 8), 256, 0, stream>>>(   // 216 + 2048
            degW, Wsw, atoms, bonds, edges, feats, degB);
        nfp_gemm_kernel<<<MROWS / BM, 256, 0, stream>>>(            // 2048 blocks
            feats, Wsw + (size_t)DEG * FRAG_SHORTS, bias, out);
        nfp_fixup_kernel<<<MROWS / 256, 256, 0, stream>>>(          // 256 blocks
            feats, degB, degW, bias, out);
    } else if (ws_size >= WSW_ALL + ATH_B) {
        unsigned short* Wsw    = (unsigned short*)d_ws;
        unsigned short* atomsH = (unsigned short*)((char*)d_ws + WSW_ALL);
        const int nWblk = (6 * 16 * NKT * 64 + 255) / 256;
        convert_pre_kernel<<<nWblk + 2048, 256, 0, stream>>>(degW, Wsw, atoms, atomsH, nWblk);
        nfp_fused_kernel<2><<<MROWS / MT, 256, 0, stream>>>(
            atoms, atomsH, bonds, edges, Wsw, degW, bias, out);
    } else if (ws_size >= WSW_ALL) {
        unsigned short* Wsw = (unsigned short*)d_ws;
        convert_w_kernel<<<(6 * 16 * NKT * 64 + 255) / 256, 256, 0, stream>>>(degW, Wsw, 1);
        nfp_fused_kernel<1><<<MROWS / MT, 256, 0, stream>>>(
            atoms, nullptr, bonds, edges, Wsw, degW, bias, out);
    } else if (ws_size >= WSW_ONE) {
        unsigned short* Wsw = (unsigned short*)d_ws;
        convert_w_kernel<<<(16 * NKT * 64 + 255) / 256, 256, 0, stream>>>(degW, Wsw, 0);
        nfp_fused_kernel<0><<<MROWS / MT, 256, 0, stream>>>(
            atoms, nullptr, bonds, edges, Wsw, degW, bias, out);
    } else {
        nfp_conv_fallback<<<BATCH * (NATOMS / FMT), 256, 0, stream>>>(
            atoms, bonds, edges, degW, bias, out);
    }
}